// Round 8
// baseline (125.360 us; speedup 1.0000x reference)
//
#include <hip/hip_runtime.h>
#include <hip/hip_bf16.h>

typedef __attribute__((ext_vector_type(8))) short bf16x8;
typedef __attribute__((ext_vector_type(16))) float f32x16;

#define H 4096
#define W 4096
#define KH 31
#define KW 31
#define OH 4066
#define OW 4066

#define BROWS 32           // output rows per block
#define BCOLS 192          // output cols per block (2 waves x 96)
#define NT 3               // x-tiles (32 wide) per wave
#define SROWS 62           // BROWS + KH - 1 staged rows
#define SPITCH 256         // padded staged cols (254 used), row = 512 B
#define SPB 512

// fp32 -> bf16 round-to-nearest-even (for the A-table pre-kernel)
__device__ __forceinline__ unsigned short bf16rne_s(float f) {
    unsigned u = __builtin_bit_cast(unsigned, f);
    u += 0x7fffu + ((u >> 16) & 1u);
    return (unsigned short)(u >> 16);
}

// bf16 A-frag table af[(dy*4 + c)*64 + lane] : bf16x8
//   elem e: K[dy][16c + 8*(lane>>5) + e - (lane&31)], 0 outside band.
__global__ void build_afrag_kernel(const float* __restrict__ Kf,
                                   unsigned short* __restrict__ af) {
    for (int i = threadIdx.x; i < KH * 4 * 64; i += 256) {
        const int dy = i >> 8;
        const int c  = (i >> 6) & 3;
        const int l  = i & 63;
        const int lr = l & 31, lh = l >> 5;
        unsigned short v[8];
        #pragma unroll
        for (int e = 0; e < 8; ++e) {
            const int idx = 16 * c + 8 * lh + e - lr;
            const float f = (idx >= 0 && idx < KW) ? Kf[dy * KW + idx] : 0.0f;
            v[e] = bf16rne_s(f);
        }
        *reinterpret_cast<bf16x8*>(af + (size_t)i * 8) =
            *reinterpret_cast<bf16x8*>(v);
    }
}

__global__ __launch_bounds__(128, 2)
void conv2d_mfma_bf16(const float* __restrict__ X,
                      const unsigned short* __restrict__ af,
                      float* __restrict__ out) {
    __shared__ unsigned short Xs[SROWS * SPITCH];   // 31744 B -> 5 blocks/CU
    char* xsb = (char*)Xs;

    const int tid = threadIdx.x;   // 0..127
    const int l   = tid & 63;
    const int lr  = l & 31;        // B col (= y) lane index
    const int lh  = l >> 5;        // k-half
    const int wv  = tid >> 6;      // 0..1 -> x col group (96 each)
    const int by0 = blockIdx.y * BROWS;
    const int bx0 = blockIdx.x * BCOLS;
    const int cbase = 96 * wv;

    // ---------- stage X tile: fp32 -> bf16 (packed cvt), XOR-swizzled ----------
    // 62 rows x 64 float4 = 3968 = 31 full iterations of 128 threads.
    for (int g = tid; g < SROWS * (SPITCH / 4); g += 128) {
        const int r  = g >> 6;            // SPITCH/4 = 64
        const int c0 = (g & 63) * 4;
        const int gy = by0 + r;
        const int gx = bx0 + c0;
        float4 v = make_float4(0.f, 0.f, 0.f, 0.f);
        if (gy < H) {
            const float* row = X + (size_t)gy * W;
            if (gx + 3 < W) {
                v = *(const float4*)(row + gx);
            } else {
                if (gx + 0 < W) v.x = row[gx + 0];
                if (gx + 1 < W) v.y = row[gx + 1];
                if (gx + 2 < W) v.z = row[gx + 2];
            }
        }
        __hip_bfloat162 p0 = __float22bfloat162_rn(make_float2(v.x, v.y));
        __hip_bfloat162 p1 = __float22bfloat162_rn(make_float2(v.z, v.w));
        unsigned u0, u1;
        __builtin_memcpy(&u0, &p0, 4);
        __builtin_memcpy(&u1, &p1, 4);
        uint2 packed = make_uint2(u0, u1);
        const int byte = r * SPB + c0 * 2;
        *(uint2*)(xsb + (byte ^ ((r & 7) << 4))) = packed;
    }
    __syncthreads();

    // ---------- main loop: no barriers, LDS read-only ----------
    f32x16 acc[NT] = {};
    const bf16x8* A = (const bf16x8*)af;

    for (int dy = 0; dy < KH; ++dy) {
        // A-frags: 4 coalesced 16B loads (L1/L2-hot table, tile-independent)
        bf16x8 a[4];
        #pragma unroll
        for (int c = 0; c < 4; ++c) a[c] = A[(dy * 4 + c) * 64 + l];

        // B-frags: 8 sliding 16-wide x-chunks at rows rr = dy + lr
        const int rr = dy + lr;            // <= 61
        const int rowbyte = rr * SPB;
        const int swz = (rr & 7) << 4;
        bf16x8 bb[2 * NT + 2];
        #pragma unroll
        for (int m = 0; m < 2 * NT + 2; ++m) {
            const int byte = rowbyte + (cbase + 16 * m) * 2 + 16 * lh;
            bb[m] = *(const bf16x8*)(xsb + (byte ^ swz));   // ds_read_b128
        }

        // 3 x-tiles x 4 k-chunks; tile t uses chunks 2t..2t+3
        __builtin_amdgcn_s_setprio(1);
        #pragma unroll
        for (int t = 0; t < NT; ++t) {
            #pragma unroll
            for (int c = 0; c < 4; ++c) {
                acc[t] = __builtin_amdgcn_mfma_f32_32x32x16_bf16(
                             a[c], bb[2 * t + c], acc[t], 0, 0, 0);
            }
        }
        __builtin_amdgcn_s_setprio(0);
    }

    // ---------- epilogue: D row = x = (reg&3)+8*(reg>>2)+4*lh, col = y = lr ----
    const int oy = by0 + lr;
    if (oy < OH) {
        float* orow = out + (size_t)oy * OW;
        #pragma unroll
        for (int t = 0; t < NT; ++t) {
            #pragma unroll
            for (int q = 0; q < 4; ++q) {
                const int x = bx0 + cbase + 32 * t + 8 * q + 4 * lh;
                if (x + 3 < OW) {
                    float4 vv = make_float4(acc[t][4*q+0], acc[t][4*q+1],
                                            acc[t][4*q+2], acc[t][4*q+3]);
                    *(float4*)(orow + x) = vv;
                } else {
                    #pragma unroll
                    for (int e = 0; e < 4; ++e)
                        if (x + e < OW) orow[x + e] = acc[t][4*q+e];
                }
            }
        }
    }
}

extern "C" void kernel_launch(void* const* d_in, const int* in_sizes, int n_in,
                              void* d_out, int out_size, void* d_ws, size_t ws_size,
                              hipStream_t stream) {
    const float* X  = (const float*)d_in[0];
    const float* Kf = (const float*)d_in[1];
    float* out = (float*)d_out;
    unsigned short* af = (unsigned short*)d_ws;   // 126976 B

    build_afrag_kernel<<<1, 256, 0, stream>>>(Kf, af);
    dim3 grid((OW + BCOLS - 1) / BCOLS, (OH + BROWS - 1) / BROWS);  // 22 x 128
    conv2d_mfma_bf16<<<grid, dim3(128), 0, stream>>>(X, af, out);
}

// Round 9
// 97.952 us; speedup vs baseline: 1.2798x; 1.2798x over previous
//
#include <hip/hip_runtime.h>
#include <hip/hip_bf16.h>

typedef __attribute__((ext_vector_type(8))) short bf16x8;
typedef __attribute__((ext_vector_type(16))) float f32x16;

#define H 4096
#define W 4096
#define KH 31
#define KW 31
#define OH 4066
#define OW 4066

#define BROWS 32           // output rows per block
#define BCOLS 256          // output cols per block (4 waves x 64)
#define SROWS 62           // BROWS + KH - 1 staged rows
#define SPITCH 312         // padded staged cols (318 needed? no: 256+62=318!)
// NOTE: wave wv reads cols [64*wv, 64*wv+64+62) -> max 3*64+126 = 318 cols.
// SPITCH must cover 318. Keep 320 for waves' reads; instead trim LDS by rows?
// -> can't trim rows. Use SPITCH 320 but force 4 blocks via launch_bounds.
#undef SPITCH
#define SPITCH 320
#define SPB 640

// fp32 -> bf16 round-to-nearest-even (A-table pre-kernel)
__device__ __forceinline__ unsigned short bf16rne_s(float f) {
    unsigned u = __builtin_bit_cast(unsigned, f);
    u += 0x7fffu + ((u >> 16) & 1u);
    return (unsigned short)(u >> 16);
}

// bf16 A-frag table af[(dy*4 + c)*64 + lane] : bf16x8
//   elem e: K[dy][16c + 8*(lane>>5) + e - (lane&31)], 0 outside band.
__global__ void build_afrag_kernel(const float* __restrict__ Kf,
                                   unsigned short* __restrict__ af) {
    for (int i = threadIdx.x; i < KH * 4 * 64; i += 256) {
        const int dy = i >> 8;
        const int c  = (i >> 6) & 3;
        const int l  = i & 63;
        const int lr = l & 31, lh = l >> 5;
        unsigned short v[8];
        #pragma unroll
        for (int e = 0; e < 8; ++e) {
            const int idx = 16 * c + 8 * lh + e - lr;
            const float f = (idx >= 0 && idx < KW) ? Kf[dy * KW + idx] : 0.0f;
            v[e] = bf16rne_s(f);
        }
        *reinterpret_cast<bf16x8*>(af + (size_t)i * 8) =
            *reinterpret_cast<bf16x8*>(v);
    }
}

#define LOADA(aX, dy_) do {                                                   \
    _Pragma("unroll")                                                         \
    for (int c = 0; c < 4; ++c) aX[c] = A[((dy_) * 4 + c) * 64 + l];          \
} while (0)

#define LOADB(bX, dy_) do {                                                   \
    const int _rr = (dy_) + lr;                                               \
    const int _rb = _rr * SPB;                                                \
    const int _sw = (_rr & 7) << 4;                                           \
    _Pragma("unroll")                                                         \
    for (int m = 0; m < 6; ++m) {                                             \
        const int _ba = _rb + (cbase + 16 * m) * 2 + 16 * lh;                 \
        bX[m] = *(const bf16x8*)(xsb + (_ba ^ _sw));                          \
    }                                                                         \
} while (0)

#define DOMFMA(aX, bX) do {                                                   \
    __builtin_amdgcn_s_setprio(1);                                            \
    _Pragma("unroll")                                                         \
    for (int t = 0; t < 2; ++t) {                                             \
        _Pragma("unroll")                                                     \
        for (int c = 0; c < 4; ++c) {                                         \
            acc[t] = __builtin_amdgcn_mfma_f32_32x32x16_bf16(                 \
                         aX[c], bX[2 * t + c], acc[t], 0, 0, 0);              \
        }                                                                     \
    }                                                                         \
    __builtin_amdgcn_s_setprio(0);                                            \
} while (0)

__global__ __launch_bounds__(256, 4)
void conv2d_mfma_bf16(const float* __restrict__ X,
                      const unsigned short* __restrict__ af,
                      float* __restrict__ out) {
    __shared__ unsigned short Xs[SROWS * SPITCH];   // 39680 B
    char* xsb = (char*)Xs;

    const int tid = threadIdx.x;
    const int l   = tid & 63;
    const int lr  = l & 31;       // B col (= y) lane index
    const int lh  = l >> 5;       // k-half
    const int wv  = tid >> 6;     // 0..3 -> x col group
    const int by0 = blockIdx.y * BROWS;
    const int bx0 = blockIdx.x * BCOLS;
    const int cbase = 64 * wv;

    // ---------- stage X tile: fp32 -> bf16 (packed cvt), XOR-swizzled ----------
    for (int g = tid; g < SROWS * (SPITCH / 4); g += 256) {
        const int r  = g / (SPITCH / 4);
        const int c0 = (g - r * (SPITCH / 4)) * 4;
        const int gy = by0 + r;
        const int gx = bx0 + c0;
        float4 v = make_float4(0.f, 0.f, 0.f, 0.f);
        if (gy < H) {
            const float* row = X + (size_t)gy * W;
            if (gx + 3 < W) {
                v = *(const float4*)(row + gx);
            } else {
                if (gx + 0 < W) v.x = row[gx + 0];
                if (gx + 1 < W) v.y = row[gx + 1];
                if (gx + 2 < W) v.z = row[gx + 2];
            }
        }
        __hip_bfloat162 p0 = __float22bfloat162_rn(make_float2(v.x, v.y));
        __hip_bfloat162 p1 = __float22bfloat162_rn(make_float2(v.z, v.w));
        unsigned u0, u1;
        __builtin_memcpy(&u0, &p0, 4);
        __builtin_memcpy(&u1, &p1, 4);
        uint2 packed = make_uint2(u0, u1);
        const int byte = r * SPB + c0 * 2;
        *(uint2*)(xsb + (byte ^ ((r & 7) << 4))) = packed;
    }
    __syncthreads();

    // ---------- main loop: no barriers, LDS read-only, A double-buffered ------
    f32x16 acc[2] = {};
    const bf16x8* A = (const bf16x8*)af;

    bf16x8 a0[4], a1[4], b0[6];

    LOADA(a0, 0);
    #pragma unroll 1
    for (int d = 0; d <= 28; d += 2) {
        LOADA(a1, d + 1);        // prefetch A for dy+1 (L2 latency off-path)
        LOADB(b0, d);
        DOMFMA(a0, b0);
        LOADA(a0, d + 2);        // prefetch A for dy+2 (d=28 -> dy=30)
        LOADB(b0, d + 1);
        DOMFMA(a1, b0);
    }
    LOADB(b0, 30);
    DOMFMA(a0, b0);              // dy = 30

    // ---------- epilogue: D row = x = (reg&3)+8*(reg>>2)+4*lh, col = y = lr ----
    const int oy = by0 + lr;
    if (oy < OH) {
        float* orow = out + (size_t)oy * OW;
        #pragma unroll
        for (int t = 0; t < 2; ++t) {
            #pragma unroll
            for (int q = 0; q < 4; ++q) {
                const int x = bx0 + cbase + 32 * t + 8 * q + 4 * lh;
                if (x + 3 < OW) {
                    float4 vv = make_float4(acc[t][4*q+0], acc[t][4*q+1],
                                            acc[t][4*q+2], acc[t][4*q+3]);
                    *(float4*)(orow + x) = vv;
                } else {
                    #pragma unroll
                    for (int e = 0; e < 4; ++e)
                        if (x + e < OW) orow[x + e] = acc[t][4*q+e];
                }
            }
        }
    }
}

extern "C" void kernel_launch(void* const* d_in, const int* in_sizes, int n_in,
                              void* d_out, int out_size, void* d_ws, size_t ws_size,
                              hipStream_t stream) {
    const float* X  = (const float*)d_in[0];
    const float* Kf = (const float*)d_in[1];
    float* out = (float*)d_out;
    unsigned short* af = (unsigned short*)d_ws;   // 126976 B

    build_afrag_kernel<<<1, 256, 0, stream>>>(Kf, af);
    dim3 grid((OW + BCOLS - 1) / BCOLS, (OH + BROWS - 1) / BROWS);  // 16 x 128
    conv2d_mfma_bf16<<<grid, dim3(256), 0, stream>>>(X, af, out);
}

// Round 10
// 96.935 us; speedup vs baseline: 1.2932x; 1.0105x over previous
//
#include <hip/hip_runtime.h>
#include <hip/hip_bf16.h>

typedef __attribute__((ext_vector_type(8))) short bf16x8;
typedef __attribute__((ext_vector_type(16))) float f32x16;

#define H 4096
#define W 4096
#define KH 31
#define KW 31
#define OH 4066
#define OW 4066

#define BROWS 64           // output rows per block (2 y-halves x 32)
#define BCOLS 128          // output cols per block (2 x-halves x 64)
#define SROWS 94           // BROWS + KH - 1 staged rows
#define SPITCH 168         // staged cols (158 used), row = 336 B
#define SPB 336            // 84 dwords = 20 mod 32 banks -> natural row stagger

// fp32 -> bf16 round-to-nearest-even (A-table pre-kernel)
__device__ __forceinline__ unsigned short bf16rne_s(float f) {
    unsigned u = __builtin_bit_cast(unsigned, f);
    u += 0x7fffu + ((u >> 16) & 1u);
    return (unsigned short)(u >> 16);
}

// bf16 A-frag table af[(dy*4 + c)*64 + lane] : bf16x8
//   elem e: K[dy][16c + 8*(lane>>5) + e - (lane&31)], 0 outside band.
__global__ void build_afrag_kernel(const float* __restrict__ Kf,
                                   unsigned short* __restrict__ af) {
    for (int i = threadIdx.x; i < KH * 4 * 64; i += 256) {
        const int dy = i >> 8;
        const int c  = (i >> 6) & 3;
        const int l  = i & 63;
        const int lr = l & 31, lh = l >> 5;
        unsigned short v[8];
        #pragma unroll
        for (int e = 0; e < 8; ++e) {
            const int idx = 16 * c + 8 * lh + e - lr;
            const float f = (idx >= 0 && idx < KW) ? Kf[dy * KW + idx] : 0.0f;
            v[e] = bf16rne_s(f);
        }
        *reinterpret_cast<bf16x8*>(af + (size_t)i * 8) =
            *reinterpret_cast<bf16x8*>(v);
    }
}

__global__ __launch_bounds__(256, 5)
void conv2d_mfma_bf16(const float* __restrict__ X,
                      const unsigned short* __restrict__ af,
                      float* __restrict__ out) {
    __shared__ unsigned short Xs[SROWS * SPITCH];   // 31584 B -> 5 blocks/CU
    char* xsb = (char*)Xs;

    const int tid = threadIdx.x;
    const int l   = tid & 63;
    const int lr  = l & 31;       // B col (= y) lane index
    const int lh  = l >> 5;       // k-half
    const int wv  = tid >> 6;     // 0..3
    const int rbase = 32 * (wv & 1);    // y-half
    const int cbase = 64 * (wv >> 1);   // x-half
    const int by0 = blockIdx.y * BROWS;
    const int bx0 = blockIdx.x * BCOLS;

    // ---------- stage X tile: fp32 -> bf16 (packed cvt), natural stagger -----
    // 94 rows x 42 float4 = 3948 slots.
    for (int g = tid; g < SROWS * (SPITCH / 4); g += 256) {
        const int r  = g / (SPITCH / 4);
        const int ce = (g - r * (SPITCH / 4)) * 4;   // col element 0..164
        const int gy = by0 + r;
        const int gx = bx0 + ce;
        float4 v = make_float4(0.f, 0.f, 0.f, 0.f);
        if (gy < H) {
            const float* row = X + (size_t)gy * W;
            if (gx + 3 < W) {
                v = *(const float4*)(row + gx);
            } else {
                if (gx + 0 < W) v.x = row[gx + 0];
                if (gx + 1 < W) v.y = row[gx + 1];
                if (gx + 2 < W) v.z = row[gx + 2];
            }
        }
        __hip_bfloat162 p0 = __float22bfloat162_rn(make_float2(v.x, v.y));
        __hip_bfloat162 p1 = __float22bfloat162_rn(make_float2(v.z, v.w));
        unsigned u0, u1;
        __builtin_memcpy(&u0, &p0, 4);
        __builtin_memcpy(&u1, &p1, 4);
        uint2 packed = make_uint2(u0, u1);
        *(uint2*)(xsb + r * SPB + ce * 2) = packed;   // 8B-aligned
    }
    __syncthreads();

    // ---------- main loop: no barriers, LDS read-only ----------
    f32x16 acc[2] = {};
    const bf16x8* A = (const bf16x8*)af;

    for (int dy = 0; dy < KH; ++dy) {
        // A-frags: 4 coalesced 16B loads (L1/L2-hot table, same for all waves)
        bf16x8 a[4];
        #pragma unroll
        for (int c = 0; c < 4; ++c) a[c] = A[(dy * 4 + c) * 64 + l];

        // B-frags: 6 sliding 16-wide x-chunks at rows rr = rbase + dy + lr.
        // Row stagger (336B = 20 banks/row) spreads lanes across bank quads.
        const int rr = rbase + dy + lr;          // <= 93
        const char* rowp = xsb + rr * SPB + cbase * 2 + 16 * lh;
        bf16x8 bb[6];
        #pragma unroll
        for (int m = 0; m < 6; ++m) {
            bb[m] = *(const bf16x8*)(rowp + 32 * m);   // ds_read_b128, 16B-aligned
        }

        // 2 x-tiles x 4 k-chunks; tile t uses chunks 2t..2t+3
        #pragma unroll
        for (int t = 0; t < 2; ++t) {
            #pragma unroll
            for (int c = 0; c < 4; ++c) {
                acc[t] = __builtin_amdgcn_mfma_f32_32x32x16_bf16(
                             a[c], bb[2 * t + c], acc[t], 0, 0, 0);
            }
        }
    }

    // ---------- epilogue: D row = x = (reg&3)+8*(reg>>2)+4*lh, col = y = lr ----
    const int oy = by0 + rbase + lr;
    if (oy < OH) {
        float* orow = out + (size_t)oy * OW;
        #pragma unroll
        for (int t = 0; t < 2; ++t) {
            #pragma unroll
            for (int q = 0; q < 4; ++q) {
                const int x = bx0 + cbase + 32 * t + 8 * q + 4 * lh;
                if (x + 3 < OW) {
                    float4 vv = make_float4(acc[t][4*q+0], acc[t][4*q+1],
                                            acc[t][4*q+2], acc[t][4*q+3]);
                    *(float4*)(orow + x) = vv;
                } else {
                    #pragma unroll
                    for (int e = 0; e < 4; ++e)
                        if (x + e < OW) orow[x + e] = acc[t][4*q+e];
                }
            }
        }
    }
}

extern "C" void kernel_launch(void* const* d_in, const int* in_sizes, int n_in,
                              void* d_out, int out_size, void* d_ws, size_t ws_size,
                              hipStream_t stream) {
    const float* X  = (const float*)d_in[0];
    const float* Kf = (const float*)d_in[1];
    float* out = (float*)d_out;
    unsigned short* af = (unsigned short*)d_ws;   // 126976 B

    build_afrag_kernel<<<1, 256, 0, stream>>>(Kf, af);
    dim3 grid((OW + BCOLS - 1) / BCOLS, (OH + BROWS - 1) / BROWS);  // 32 x 64
    conv2d_mfma_bf16<<<grid, dim3(256), 0, stream>>>(X, af, out);
}